// Round 4
// baseline (309.568 us; speedup 1.0000x reference)
//
#include <hip/hip_runtime.h>
#include <hip/hip_bf16.h>

#define C   64
#define Hh  128
#define Ww  128
#define HW  16384

typedef __attribute__((ext_vector_type(8))) short bf16x8;
typedef __attribute__((ext_vector_type(4))) float f32x4;

__device__ __forceinline__ unsigned short f2bf(float f) {
    unsigned u = __builtin_bit_cast(unsigned, f);
    unsigned r = (u + 0x7fff + ((u >> 16) & 1)) >> 16;
    return (unsigned short)r;
}
__device__ __forceinline__ float bf2f(unsigned short h) {
    unsigned u = ((unsigned)h) << 16;
    return __builtin_bit_cast(float, u);
}

// ---------------------------------------------------------------------------
// Prep: fold BN scale into 1x1 proj weights (bf16), compute shifts, and pack
// conv weights to wp[ch2][tap9][co64][ci32] bf16 for each conv half.
// ---------------------------------------------------------------------------
__global__ __launch_bounds__(256) void prep_kernel(
    const float* __restrict__ pu_w, const float* __restrict__ pu_g,
    const float* __restrict__ pu_b, const float* __restrict__ pu_m,
    const float* __restrict__ pu_v,
    const float* __restrict__ pv_w, const float* __restrict__ pv_g,
    const float* __restrict__ pv_b, const float* __restrict__ pv_m,
    const float* __restrict__ pv_v,
    const float* __restrict__ conv_w,
    short* __restrict__ pwu, short* __restrict__ pwv,
    short* __restrict__ wpu, short* __restrict__ wpv,
    float* __restrict__ shu, float* __restrict__ shv)
{
    const int idx = blockIdx.x * 256 + threadIdx.x;
    if (idx < 8192) {                       // proj weights, scale-folded
        const int c  = idx >> 12;
        const int r  = idx & 4095;
        const int co = r >> 6;
        const float* w = c ? pv_w : pu_w;
        const float* g = c ? pv_g : pu_g;
        const float* vv = c ? pv_v : pu_v;
        const float scale = g[co] * rsqrtf(vv[co] + 1e-5f);
        const int ci = r & 63;
        (c ? pwv : pwu)[r] = (short)f2bf(w[co * 64 + ci] * scale);
    } else if (idx < 81920) {               // conv weights repack
        const int flat = idx - 8192;
        const int c  = flat / 36864;
        const int r  = flat % 36864;
        const int ch  = r / 18432;
        const int r2  = r % 18432;
        const int tap = r2 / 2048;
        const int r3  = r2 & 2047;
        const int co = r3 >> 5, ci = r3 & 31;
        const float src = conv_w[(size_t)(co * 128 + c * 64 + ch * 32 + ci) * 9 + tap];
        (c ? wpv : wpu)[((ch * 9 + tap) * 64 + co) * 32 + ci] = (short)f2bf(src);
    } else if (idx < 82048) {               // shifts
        const int r  = idx - 81920;
        const int c  = r >> 6, co = r & 63;
        const float* g = c ? pv_g : pu_g;
        const float* b = c ? pv_b : pu_b;
        const float* m = c ? pv_m : pu_m;
        const float* vv = c ? pv_v : pu_v;
        const float scale = g[co] * rsqrtf(vv[co] + 1e-5f);
        (c ? shv : shu)[co] = b[co] - m[co] * scale;
    }
}

// ---------------------------------------------------------------------------
// Fused proj(1x1+BN+ReLU) + conv3x3 per 8x32 output tile.
// Phase 1: stage raw fp32 halo (10x34 cells x 64ci) -> LDS bf16 [cell][ci].
// Phase 2: proj in-place in LDS via MFMA (wave-disjoint 16-row M-tiles).
//          *** Padding cells (outside image) are forced to 0, matching the
//          reference's zero-pad-AFTER-relu semantics. ***
// Phase 3: implicit-GEMM conv: A=weights (LDS, 3-tap groups), B=activations,
//          4x4 frags/wave (64co x 64px). Output bf16 ot[img][co][hw].
// grid: (64 tiles, 8 img, 2 uv). LDS 66.3 KB -> 2 blocks/CU.
// ---------------------------------------------------------------------------
__global__ __launch_bounds__(256, 2) void fused_kernel(
    const float* __restrict__ ug, const float* __restrict__ vg,
    const short* __restrict__ pwu, const short* __restrict__ pwv,
    const float* __restrict__ shu, const float* __restrict__ shv,
    const short* __restrict__ wpu, const short* __restrict__ wpv,
    short* __restrict__ oug, short* __restrict__ ovg)
{
    __shared__ short xs[352 * 72];     // [cell][64 + 8 pad]; raw ci then proj co
    __shared__ short wbuf[3 * 64 * 40];// proj pw [co][72] OR conv taps [3][64][40]
    __shared__ float ssh[64];

    const int isv = blockIdx.z;
    const float* x  = isv ? vg  : ug;
    const short* pw = isv ? pwv : pwu;
    const float* sh = isv ? shv : shu;
    const short* wp = isv ? wpv : wpu;
    short*       ot = isv ? ovg : oug;

    const int img  = blockIdx.y;
    const int tile = blockIdx.x;
    const int tx = tile & 3, ty = tile >> 2;
    const int h0 = ty * 8, w0 = tx * 32;
    const int tid = threadIdx.x;
    const int wq = tid >> 6;
    const int lane = tid & 63;
    const int lx = lane & 15;
    const int q  = lane >> 4;
    const int q8 = q * 8;

    // ---- Phase 1: stage raw halo, fp32 [ci][h][w] -> bf16 LDS [cell][ci] ----
    const float* xi = x + (size_t)img * C * HW;
    for (int it = 0; it < 43; ++it) {
        const int idx = it * 256 + tid;      // (ci-pair p, cell)
        if (idx < 10880) {
            const int p    = idx / 340;
            const int cell = idx - p * 340;
            const int r = cell / 34, cc = cell - r * 34;
            const int gh = h0 - 1 + r, gw = w0 - 1 + cc;
            int pk = 0;
            if (gh >= 0 && gh < Hh && gw >= 0 && gw < Ww) {
                const float a = xi[(size_t)(2 * p) * HW + gh * Ww + gw];
                const float b = xi[(size_t)(2 * p + 1) * HW + gh * Ww + gw];
                pk = (int)f2bf(a) | ((int)f2bf(b) << 16);
            }
            *(int*)&xs[cell * 72 + 2 * p] = pk;
        }
    }
    // stage proj weights [co][72] + shifts
#pragma unroll
    for (int itr = 0; itr < 2; ++itr) {
        const int idx = itr * 256 + tid;     // 512 chunks of 16B
        const int oct = idx & 7, co = idx >> 3;
        *(int4*)&wbuf[co * 72 + oct * 8] = *(const int4*)&pw[co * 64 + oct * 8];
    }
    if (tid < 64) ssh[tid] = sh[tid];
    __syncthreads();

    // ---- Phase 2: proj in place. Wave wq owns M-tiles wq, wq+4, ... (<22) ----
    {
        bf16x8 bw[4][2];
#pragma unroll
        for (int nt = 0; nt < 4; ++nt)
#pragma unroll
            for (int kc = 0; kc < 2; ++kc)
                bw[nt][kc] = *(const bf16x8*)&wbuf[(nt * 16 + lx) * 72 + kc * 32 + q8];

        for (int mt = wq; mt < 22; mt += 4) {
            const bf16x8 a0 = *(const bf16x8*)&xs[(mt * 16 + lx) * 72 + q8];
            const bf16x8 a1 = *(const bf16x8*)&xs[(mt * 16 + lx) * 72 + 32 + q8];
            f32x4 pa[4];
#pragma unroll
            for (int nt = 0; nt < 4; ++nt) {
                pa[nt] = (f32x4){0.f, 0.f, 0.f, 0.f};
                pa[nt] = __builtin_amdgcn_mfma_f32_16x16x32_bf16(a0, bw[nt][0], pa[nt], 0, 0, 0);
                pa[nt] = __builtin_amdgcn_mfma_f32_16x16x32_bf16(a1, bw[nt][1], pa[nt], 0, 0, 0);
            }
            // write back relu(y+shift) as bf16: row = mt*16+q*4+r, col = co.
            // Padding cells (outside image) and cells >= 340 get 0 so the conv
            // sees the reference's zero padding (pad applied AFTER proj+relu).
#pragma unroll
            for (int r = 0; r < 4; ++r) {
                const int cell = mt * 16 + q * 4 + r;
                const int rr = cell / 34, cc = cell - rr * 34;
                const int gh = h0 - 1 + rr, gw = w0 - 1 + cc;
                const bool inb = (cell < 340) & (gh >= 0) & (gh < Hh) & (gw >= 0) & (gw < Ww);
#pragma unroll
                for (int nt = 0; nt < 4; ++nt) {
                    const float vv = fmaxf(pa[nt][r] + ssh[nt * 16 + lx], 0.f);
                    xs[cell * 72 + nt * 16 + lx] = inb ? (short)f2bf(vv) : (short)0;
                }
            }
        }
    }
    __syncthreads();

    // ---- Phase 3: conv 3x3. acc = 64co x 64px per wave ----
    f32x4 acc[4][4];
#pragma unroll
    for (int mt = 0; mt < 4; ++mt)
#pragma unroll
        for (int nt = 0; nt < 4; ++nt) acc[mt][nt] = (f32x4){0.f, 0.f, 0.f, 0.f};

    for (int ch = 0; ch < 2; ++ch) {
        for (int ky = 0; ky < 3; ++ky) {
            __syncthreads();   // previous wbuf readers done
            // stage taps (ch, ky, kx=0..2): [kx][co][40]
#pragma unroll
            for (int itr = 0; itr < 3; ++itr) {
                const int idx = itr * 256 + tid;  // 768 chunks of 16B
                const int oct = idx & 3;
                const int co  = (idx >> 2) & 63;
                const int tl  = idx >> 8;
                *(int4*)&wbuf[(tl * 64 + co) * 40 + oct * 8] =
                    *(const int4*)&wp[(((ch * 9 + ky * 3 + tl) * 64) + co) * 32 + oct * 8];
            }
            __syncthreads();
#pragma unroll
            for (int kx = 0; kx < 3; ++kx) {
                bf16x8 a[4], b[4];
#pragma unroll
                for (int mt = 0; mt < 4; ++mt)
                    a[mt] = *(const bf16x8*)&wbuf[(kx * 64 + mt * 16 + lx) * 40 + q8];
#pragma unroll
                for (int nt = 0; nt < 4; ++nt) {
                    const int cell = (2 * wq + (nt >> 1) + ky) * 34 + (nt & 1) * 16 + lx + kx;
                    b[nt] = *(const bf16x8*)&xs[cell * 72 + ch * 32 + q8];
                }
#pragma unroll
                for (int mt = 0; mt < 4; ++mt)
#pragma unroll
                    for (int nt = 0; nt < 4; ++nt)
                        acc[mt][nt] = __builtin_amdgcn_mfma_f32_16x16x32_bf16(a[mt], b[nt], acc[mt][nt], 0, 0, 0);
            }
        }
    }

    // ---- epilogue: ot[img][co][h][w] bf16 ----
    short* ob = ot + (size_t)img * C * HW;
#pragma unroll
    for (int mt = 0; mt < 4; ++mt)
#pragma unroll
        for (int nt = 0; nt < 4; ++nt)
#pragma unroll
            for (int r = 0; r < 4; ++r) {
                const int co = mt * 16 + q * 4 + r;
                const int h = h0 + 2 * wq + (nt >> 1);
                const int w = w0 + (nt & 1) * 16 + lx;
                ob[(size_t)co * HW + h * Ww + w] = (short)f2bf(acc[mt][nt][r]);
            }
}

// ---------------------------------------------------------------------------
// Cross broadcast add: out[b,sx,sy,co,hw] = ou[b4+sx] + ov[b4+sy] + bias.
// bf16 inputs, fp32 output; 8 px per thread.
// ---------------------------------------------------------------------------
__global__ __launch_bounds__(256) void addb_kernel(
    const unsigned short* __restrict__ ou, const unsigned short* __restrict__ ov,
    const float* __restrict__ bias, float* __restrict__ out)
{
    const size_t i8 = (size_t)blockIdx.x * 256 + threadIdx.x;  // 8 px
    const int    hw8 = (int)(i8 & 2047);           // HW/8
    const size_t qq  = i8 >> 11;
    const int co = (int)(qq & 63);
    const size_t p = qq >> 6;
    const int sy = (int)(p & 3);
    const int sx = (int)((p >> 2) & 3);
    const int b  = (int)(p >> 4);

    const int4 lu = *(const int4*)&ou[((size_t)(b * 4 + sx) * C + co) * HW + hw8 * 8];
    const int4 lv = *(const int4*)&ov[((size_t)(b * 4 + sy) * C + co) * HW + hw8 * 8];
    const float bb = bias[co];

    float r[8];
    const int uu[4] = {lu.x, lu.y, lu.z, lu.w};
    const int vv[4] = {lv.x, lv.y, lv.z, lv.w};
#pragma unroll
    for (int k = 0; k < 4; ++k) {
        r[2 * k]     = bf2f((unsigned short)(uu[k] & 0xffff)) + bf2f((unsigned short)(vv[k] & 0xffff)) + bb;
        r[2 * k + 1] = bf2f((unsigned short)((unsigned)uu[k] >> 16)) + bf2f((unsigned short)((unsigned)vv[k] >> 16)) + bb;
    }
    float4* o = (float4*)(out + i8 * 8);
    o[0] = (float4){r[0], r[1], r[2], r[3]};
    o[1] = (float4){r[4], r[5], r[6], r[7]};
}

// ---------------------------------------------------------------------------
extern "C" void kernel_launch(void* const* d_in, const int* in_sizes, int n_in,
                              void* d_out, int out_size, void* d_ws, size_t ws_size,
                              hipStream_t stream)
{
    const float* u        = (const float*)d_in[0];
    const float* v        = (const float*)d_in[1];
    const float* pu_w     = (const float*)d_in[2];
    const float* pu_gamma = (const float*)d_in[3];
    const float* pu_beta  = (const float*)d_in[4];
    const float* pu_mean  = (const float*)d_in[5];
    const float* pu_var   = (const float*)d_in[6];
    const float* pv_w     = (const float*)d_in[7];
    const float* pv_gamma = (const float*)d_in[8];
    const float* pv_beta  = (const float*)d_in[9];
    const float* pv_mean  = (const float*)d_in[10];
    const float* pv_var   = (const float*)d_in[11];
    const float* conv_w   = (const float*)d_in[12];
    const float* conv_b   = (const float*)d_in[13];
    float* out = (float*)d_out;

    char* ws = (char*)d_ws;
    short* ou  = (short*)(ws);                         // 16,777,216 B (bf16)
    short* ov  = (short*)(ws + 16777216);              // 16,777,216 B (bf16)
    char*  aux = ws + 33554432;
    short* pwu = (short*)(aux);                        // 8192 B
    short* pwv = (short*)(aux + 8192);                 // 8192 B
    short* wpu = (short*)(aux + 16384);                // 73,728 B
    short* wpv = (short*)(aux + 90112);                // 73,728 B
    float* shu = (float*)(aux + 163840);               // 256 B
    float* shv = (float*)(aux + 164096);               // 256 B

    prep_kernel<<<321, 256, 0, stream>>>(pu_w, pu_gamma, pu_beta, pu_mean, pu_var,
                                         pv_w, pv_gamma, pv_beta, pv_mean, pv_var,
                                         conv_w, pwu, pwv, wpu, wpv, shu, shv);

    dim3 gf(64, 8, 2);
    fused_kernel<<<gf, 256, 0, stream>>>(u, v, pwu, pwv, shu, shv, wpu, wpv, ou, ov);

    addb_kernel<<<16384, 256, 0, stream>>>((const unsigned short*)ou,
                                           (const unsigned short*)ov, conv_b, out);
}